// Round 5
// baseline (191.254 us; speedup 1.0000x reference)
//
#include <hip/hip_runtime.h>
#include <hip/hip_bf16.h>

// (B,T,D,H) = (4,2048,384,6), HD=64. Inputs/output f32; intermediates bf16.
#define BB   4
#define TT   2048
#define DDIM 384
#define HH   6
#define HD   64
#define BT   (BB*TT)
#define QKVC (3*DDIM)

typedef __attribute__((ext_vector_type(4))) short short4v;
typedef __attribute__((ext_vector_type(8))) short short8v;
typedef __attribute__((ext_vector_type(4))) float float4v;
typedef unsigned short u16;

static __device__ __forceinline__ u16 f2bu(float f) {
    __hip_bfloat16 h = __float2bfloat16(f);
    return __builtin_bit_cast(u16, h);
}

static __device__ __forceinline__ short8v ld_frag(const u16* p) {
    short4v a = *(const short4v*)p;
    short4v b = *(const short4v*)(p + 4);
    return __builtin_shufflevector(a, b, 0, 1, 2, 3, 4, 5, 6, 7);
}

static __device__ __forceinline__ void st8(u16* p, uint4 v) {
    *(uint2*)p       = make_uint2(v.x, v.y);
    *(uint2*)(p + 4) = make_uint2(v.z, v.w);
}

#define MFMA16(a, b, c) __builtin_amdgcn_mfma_f32_16x16x32_bf16((a), (b), (c), 0, 0, 0)

// K=16 bf16 MFMA (legacy shape, present on gfx950 per ISA §10) — builtin name
// differs across ROCm versions; probe both spellings.
#if __has_builtin(__builtin_amdgcn_mfma_f32_16x16x16_bf16)
#define MFMAK16(a, b, c) __builtin_amdgcn_mfma_f32_16x16x16_bf16((a), (b), (c), 0, 0, 0)
#elif __has_builtin(__builtin_amdgcn_mfma_f32_16x16x16bf16_1k)
#define MFMAK16(a, b, c) __builtin_amdgcn_mfma_f32_16x16x16bf16_1k((a), (b), (c), 0, 0, 0)
#else
#define MFMAK16(a, b, c) __builtin_amdgcn_mfma_f32_16x16x16bf16_1k((a), (b), (c), 0, 0, 0)
#endif

// ---------------------------------------------------------------------------
// K0 (merged prep): blocks [0,108): wqkv^T ; [108,144): wproj^T ; [144,912):
// x -> bf16 cast. One launch replaces two wtrans + removes per-iter f32->bf16
// conversion from the qkv hot loop.
// ---------------------------------------------------------------------------
__global__ __launch_bounds__(256) void prep_kernel(
    const float* __restrict__ wqkv, const float* __restrict__ wproj,
    const float* __restrict__ x,
    u16* __restrict__ wqkvT, u16* __restrict__ wprojT, u16* __restrict__ xb)
{
    const int bid = blockIdx.x;
    const int t = threadIdx.x;
    if (bid >= 144) {
        size_t base = (size_t)(bid - 144) * 4096 + (size_t)t * 16;
        const float* gp = x + base;
        __align__(16) u16 tmp[16];
        #pragma unroll
        for (int u = 0; u < 4; ++u) {
            float4 v = *(const float4*)(gp + 4 * u);
            tmp[4 * u + 0] = f2bu(v.x); tmp[4 * u + 1] = f2bu(v.y);
            tmp[4 * u + 2] = f2bu(v.z); tmp[4 * u + 3] = f2bu(v.w);
        }
        *(uint4*)(xb + base)     = *(const uint4*)tmp;
        *(uint4*)(xb + base + 8) = *(const uint4*)(tmp + 8);
        return;
    }
    const float* in; u16* out; int K, C, c0, k0;
    if (bid < 108) { in = wqkv;  out = wqkvT;  K = DDIM; C = QKVC;
                     c0 = (bid % 18) * 64; k0 = (bid / 18) * 64; }
    else           { int b2 = bid - 108; in = wproj; out = wprojT; K = DDIM; C = DDIM;
                     c0 = (b2 % 6) * 64; k0 = (b2 / 6) * 64; }
    __shared__ float tr[64][65];
    {
        int kr = t >> 2, cb = (t & 3) * 16;
        const float* gp = in + (size_t)(k0 + kr) * C + c0 + cb;
        #pragma unroll
        for (int u = 0; u < 4; ++u) {
            float4 v = *(const float4*)(gp + 4 * u);
            tr[cb + 4 * u + 0][kr] = v.x;
            tr[cb + 4 * u + 1][kr] = v.y;
            tr[cb + 4 * u + 2][kr] = v.z;
            tr[cb + 4 * u + 3][kr] = v.w;
        }
    }
    __syncthreads();
    {
        int c = t >> 2, kb = (t & 3) * 16;
        __align__(16) u16 tmp[16];
        #pragma unroll
        for (int u = 0; u < 16; ++u) tmp[u] = f2bu(tr[c][kb + u]);
        u16* op = out + (size_t)(c0 + c) * K + k0 + kb;
        *(uint4*)op       = *(const uint4*)tmp;
        *(uint4*)(op + 8) = *(const uint4*)(tmp + 8);
    }
}

// ---------------------------------------------------------------------------
// K1: qkv = xb @ wqkvT (all-bf16 staging now), RoPE fused in epilogue.
//   q,k -> [bh][t][d] bf16 ; v -> TRANSPOSED [bh][d][t] bf16.
// ---------------------------------------------------------------------------
__global__ __launch_bounds__(256) void qkv_rope_kernel(
    const u16* __restrict__ xb, const u16* __restrict__ wt,
    const float* __restrict__ cs, const float* __restrict__ sn,
    u16* __restrict__ qb, u16* __restrict__ kb, u16* __restrict__ vtb)
{
    __shared__ __align__(16) u16 xs[2][64][68];
    __shared__ __align__(16) u16 ws[2][64][68];
    const int t = threadIdx.x;
    const int wv = t >> 6, lane = t & 63, quad = lane >> 4, lo = lane & 15;
    const int r0 = blockIdx.y * 64;
    const int c0 = blockIdx.x * 64;
    const int sr = t >> 3, sd = (t & 7) * 8;

    st8(&xs[0][sr][sd],      *(const uint4*)(xb + (size_t)(r0 + sr) * DDIM + sd));
    st8(&xs[0][sr + 32][sd], *(const uint4*)(xb + (size_t)(r0 + sr + 32) * DDIM + sd));
    st8(&ws[0][sr][sd],      *(const uint4*)(wt + (size_t)(c0 + sr) * DDIM + sd));
    st8(&ws[0][sr + 32][sd], *(const uint4*)(wt + (size_t)(c0 + sr + 32) * DDIM + sd));
    __syncthreads();

    float4v acc[4] = {};
    for (int kk = 0; kk < 6; ++kk) {
        const int cur = kk & 1, nxt = cur ^ 1;
        const int kkn = (kk < 5 ? kk + 1 : 5) * 64;
        uint4 xp0 = *(const uint4*)(xb + (size_t)(r0 + sr) * DDIM + kkn + sd);
        uint4 xp1 = *(const uint4*)(xb + (size_t)(r0 + sr + 32) * DDIM + kkn + sd);
        uint4 wp0 = *(const uint4*)(wt + (size_t)(c0 + sr) * DDIM + kkn + sd);
        uint4 wp1 = *(const uint4*)(wt + (size_t)(c0 + sr + 32) * DDIM + kkn + sd);

        #pragma unroll
        for (int kf = 0; kf < 2; ++kf) {
            short8v a = ld_frag(&xs[cur][16 * wv + lo][kf * 32 + quad * 8]);
            #pragma unroll
            for (int nt = 0; nt < 4; ++nt) {
                short8v b = ld_frag(&ws[cur][nt * 16 + lo][kf * 32 + quad * 8]);
                acc[nt] = MFMA16(a, b, acc[nt]);
            }
        }
        st8(&xs[nxt][sr][sd], xp0);
        st8(&xs[nxt][sr + 32][sd], xp1);
        st8(&ws[nxt][sr][sd], wp0);
        st8(&ws[nxt][sr + 32][sd], wp1);
        __syncthreads();
    }

    const int sec = blockIdx.x / 6;     // 0=q, 1=k, 2=v
    const int h   = blockIdx.x % 6;
    const int rbase = r0 + 16 * wv + 4 * quad;
    const int bidx  = r0 >> 11;
    const int tbase = rbase & (TT - 1);

    if (sec == 2) {
        #pragma unroll
        for (int nt = 0; nt < 4; ++nt) {
            int d = nt * 16 + lo;
            unsigned a0 = f2bu(acc[nt][0]) | ((unsigned)f2bu(acc[nt][1]) << 16);
            unsigned a1 = f2bu(acc[nt][2]) | ((unsigned)f2bu(acc[nt][3]) << 16);
            u16* gp = vtb + ((size_t)(bidx * HH + h) * HD + d) * TT + tbase;
            *(uint2*)gp = make_uint2(a0, a1);
        }
    } else {
        u16* dst = (sec == 0) ? qb : kb;
        #pragma unroll
        for (int np = 0; np < 2; ++np) {
            #pragma unroll
            for (int r = 0; r < 4; ++r) {
                int tpos = tbase + r;
                int ci = np * 16 + lo;
                float cv = cs[tpos * 32 + ci];
                float sv = sn[tpos * 32 + ci];
                float x1 = acc[np][r], x2 = acc[np + 2][r];
                u16* gp = dst + ((size_t)(bidx * HH + h) * TT + tpos) * HD;
                gp[ci]      = f2bu(x1 * cv - x2 * sv);
                gp[ci + 32] = f2bu(x2 * cv + x1 * sv);
            }
        }
    }
}

// ---------------------------------------------------------------------------
// K2: MFMA flash attention, S^T formulation:
//   S^T = K·Q^T via 16x16x32 (C-layout: row=k-col=4*quad+r, col=q-row=lo).
//   That C-layout IS the A-operand layout of P for 16x16x16 MFMA (A: m=lo,
//   k=quad*4+j, chunk nt) -> exp feeds PV straight from registers. No LDS
//   round-trip, no cross-lane ops in the loop. Bias = 4 float4 loads/iter.
//   K/V ping-pong + register prefetch, ONE barrier/iter.
// ---------------------------------------------------------------------------
__global__ __launch_bounds__(256, 3) void attn_kernel(
    const u16* __restrict__ qb, const u16* __restrict__ kb, const u16* __restrict__ vtb,
    const float* __restrict__ bias, u16* __restrict__ ob)
{
    __shared__ __align__(16) u16 ks[2][64][68];
    __shared__ __align__(16) u16 vt[2][64][68];

    const int t = threadIdx.x;
    const int wv = t >> 6, lane = t & 63, quad = lane >> 4, lo = lane & 15;
    const int bh = blockIdx.y;
    const int b = bh / HH, h = bh % HH;
    const int q0 = blockIdx.x * 64;
    const int qrow = q0 + 16 * wv + lo;           // q-row owned by this lane

    // Q fragments (B-operand of S^T): straight from global, row-contiguous
    const u16* qbase = qb + ((size_t)bh * TT + qrow) * HD + quad * 8;
    short8v aq0 = __builtin_bit_cast(short8v, *(const uint4*)qbase);
    short8v aq1 = __builtin_bit_cast(short8v, *(const uint4*)(qbase + 32));

    const int sr = t >> 3, sd = (t & 7) * 8;
    const u16* kbbase = kb + (size_t)bh * TT * HD;
    const u16* vtbase = vtb + (size_t)bh * HD * TT;
    const float* brow = bias + (size_t)qrow * TT + 4 * quad;

    st8(&ks[0][sr][sd],      *(const uint4*)(kbbase + (size_t)sr * HD + sd));
    st8(&ks[0][sr + 32][sd], *(const uint4*)(kbbase + (size_t)(sr + 32) * HD + sd));
    st8(&vt[0][sr][sd],      *(const uint4*)(vtbase + (size_t)sr * TT + sd));
    st8(&vt[0][sr + 32][sd], *(const uint4*)(vtbase + (size_t)(sr + 32) * TT + sd));
    float4 bcur[4];
    #pragma unroll
    for (int nt = 0; nt < 4; ++nt) bcur[nt] = *(const float4*)(brow + nt * 16);
    __syncthreads();

    float4v oacc[4] = {};                 // [dt]: O(q=16wv+4*quad+r, d=16dt+lo)
    float lacc[4] = {0.f, 0.f, 0.f, 0.f}; // partial row-sums for q-row = lo

    for (int kt = 0; kt < TT / 64; ++kt) {
        const int cur = kt & 1, nxt = cur ^ 1;
        const int kn = (kt < 31 ? kt + 1 : 31) * 64;

        uint4 kp0 = *(const uint4*)(kbbase + (size_t)(kn + sr) * HD + sd);
        uint4 kp1 = *(const uint4*)(kbbase + (size_t)(kn + sr + 32) * HD + sd);
        uint4 vp0 = *(const uint4*)(vtbase + (size_t)sr * TT + kn + sd);
        uint4 vp1 = *(const uint4*)(vtbase + (size_t)(sr + 32) * TT + kn + sd);
        float4 bnxt[4];
        #pragma unroll
        for (int nt = 0; nt < 4; ++nt) bnxt[nt] = *(const float4*)(brow + kn + nt * 16);

        // S^T = K Q^T : A = K-frag (m = k-col), B = Q-frag (n = q-row)
        float4v s[4] = {};
        #pragma unroll
        for (int kf = 0; kf < 2; ++kf) {
            #pragma unroll
            for (int nt = 0; nt < 4; ++nt) {
                short8v kfr = ld_frag(&ks[cur][nt * 16 + lo][kf * 32 + quad * 8]);
                s[nt] = MFMA16(kfr, (kf ? aq1 : aq0), s[nt]);
            }
        }

        // exp (unshifted: scores*0.125+bias bounded ~5.6) -> P A-frags in regs
        short4v pa[4];
        #pragma unroll
        for (int nt = 0; nt < 4; ++nt) {
            float p0 = __expf(fmaf(s[nt][0], 0.125f, bcur[nt].x));
            float p1 = __expf(fmaf(s[nt][1], 0.125f, bcur[nt].y));
            float p2 = __expf(fmaf(s[nt][2], 0.125f, bcur[nt].z));
            float p3 = __expf(fmaf(s[nt][3], 0.125f, bcur[nt].w));
            lacc[nt] += (p0 + p1) + (p2 + p3);
            short4v pv = { (short)f2bu(p0), (short)f2bu(p1),
                           (short)f2bu(p2), (short)f2bu(p3) };
            pa[nt] = pv;
        }

        // O += P V  via 16x16x16: A = pa[nt] (k-chunk nt), B = V^T lane-local b64
        #pragma unroll
        for (int dt = 0; dt < 4; ++dt) {
            #pragma unroll
            for (int nt = 0; nt < 4; ++nt) {
                short4v bv = *(const short4v*)&vt[cur][dt * 16 + lo][nt * 16 + 4 * quad];
                oacc[dt] = MFMAK16(pa[nt], bv, oacc[dt]);
            }
        }

        st8(&ks[nxt][sr][sd], kp0);
        st8(&ks[nxt][sr + 32][sd], kp1);
        st8(&vt[nxt][sr][sd], vp0);
        st8(&vt[nxt][sr + 32][sd], vp1);
        #pragma unroll
        for (int nt = 0; nt < 4; ++nt) bcur[nt] = bnxt[nt];
        __syncthreads();
    }

    float l = (lacc[0] + lacc[1]) + (lacc[2] + lacc[3]);
    l += __shfl_xor(l, 16);
    l += __shfl_xor(l, 32);                 // all lanes now hold l(row=lo)
    #pragma unroll
    for (int r = 0; r < 4; ++r) {
        float lr = __shfl(l, 4 * quad + r); // fetch l for output row 4*quad+r
        float inv = 1.f / lr;
        u16* gp = ob + ((size_t)b * TT + q0 + 16 * wv + 4 * quad + r) * DDIM + h * HD + lo;
        #pragma unroll
        for (int dt = 0; dt < 4; ++dt)
            gp[dt * 16] = f2bu(oacc[dt][r] * inv);
    }
}

// ---------------------------------------------------------------------------
// K3: out = O @ w_proj (MFMA), f32 output. Ping-pong + prefetch, 1 barrier/chunk.
// ---------------------------------------------------------------------------
__global__ __launch_bounds__(256) void proj_kernel(
    const u16* __restrict__ o, const u16* __restrict__ wt, float* __restrict__ out)
{
    __shared__ __align__(16) u16 os[2][64][68];
    __shared__ __align__(16) u16 ws[2][64][68];
    const int t = threadIdx.x;
    const int wv = t >> 6, lane = t & 63, quad = lane >> 4, lo = lane & 15;
    const int r0 = blockIdx.y * 64, c0 = blockIdx.x * 64;
    const int sr = t >> 3, sd = (t & 7) * 8;

    st8(&os[0][sr][sd],      *(const uint4*)(o + (size_t)(r0 + sr) * DDIM + sd));
    st8(&os[0][sr + 32][sd], *(const uint4*)(o + (size_t)(r0 + sr + 32) * DDIM + sd));
    st8(&ws[0][sr][sd],      *(const uint4*)(wt + (size_t)(c0 + sr) * DDIM + sd));
    st8(&ws[0][sr + 32][sd], *(const uint4*)(wt + (size_t)(c0 + sr + 32) * DDIM + sd));
    __syncthreads();

    float4v acc[4] = {};
    for (int kk = 0; kk < 6; ++kk) {
        const int cur = kk & 1, nxt = cur ^ 1;
        const int kkn = (kk < 5 ? kk + 1 : 5) * 64;
        uint4 op0 = *(const uint4*)(o + (size_t)(r0 + sr) * DDIM + kkn + sd);
        uint4 op1 = *(const uint4*)(o + (size_t)(r0 + sr + 32) * DDIM + kkn + sd);
        uint4 wp0 = *(const uint4*)(wt + (size_t)(c0 + sr) * DDIM + kkn + sd);
        uint4 wp1 = *(const uint4*)(wt + (size_t)(c0 + sr + 32) * DDIM + kkn + sd);

        #pragma unroll
        for (int kf = 0; kf < 2; ++kf) {
            short8v a = ld_frag(&os[cur][16 * wv + lo][kf * 32 + quad * 8]);
            #pragma unroll
            for (int nt = 0; nt < 4; ++nt) {
                short8v bfr = ld_frag(&ws[cur][nt * 16 + lo][kf * 32 + quad * 8]);
                acc[nt] = MFMA16(a, bfr, acc[nt]);
            }
        }
        st8(&os[nxt][sr][sd], op0);
        st8(&os[nxt][sr + 32][sd], op1);
        st8(&ws[nxt][sr][sd], wp0);
        st8(&ws[nxt][sr + 32][sd], wp1);
        __syncthreads();
    }
    #pragma unroll
    for (int r = 0; r < 4; ++r) {
        float* gp = out + (size_t)(r0 + 16 * wv + 4 * quad + r) * DDIM + c0;
        #pragma unroll
        for (int nt = 0; nt < 4; ++nt)
            gp[nt * 16 + lo] = acc[nt][r];
    }
}

extern "C" void kernel_launch(void* const* d_in, const int* in_sizes, int n_in,
                              void* d_out, int out_size, void* d_ws, size_t ws_size,
                              hipStream_t stream) {
    const float* x     = (const float*)d_in[0];
    const float* bias  = (const float*)d_in[1];
    const float* cs    = (const float*)d_in[2];
    const float* sn    = (const float*)d_in[3];
    const float* wqkv  = (const float*)d_in[4];
    const float* wproj = (const float*)d_in[5];
    float* out = (float*)d_out;

    u16* wqkvT  = (u16*)d_ws;                         // [1152][384]
    u16* wprojT = wqkvT + (size_t)QKVC * DDIM;        // [384][384]
    u16* qb     = wprojT + (size_t)DDIM * DDIM;       // [bh][t][d]
    u16* kb     = qb + (size_t)BB * HH * TT * HD;     // [bh][t][d]
    u16* vtb    = kb + (size_t)BB * HH * TT * HD;     // [bh][d][t]
    u16* ob     = vtb + (size_t)BB * HH * TT * HD;    // [b][t][h*64+d]
    u16* xb     = ob + (size_t)BT * DDIM;             // [b*t][384] bf16 x
    // total ws use: ~33 MB

    prep_kernel<<<dim3(144 + BT * DDIM / 4096), 256, 0, stream>>>(
        wqkv, wproj, x, wqkvT, wprojT, xb);
    qkv_rope_kernel<<<dim3(QKVC / 64, BT / 64), 256, 0, stream>>>(
        xb, wqkvT, cs, sn, qb, kb, vtb);
    attn_kernel<<<dim3(TT / 64, BB * HH), 256, 0, stream>>>(qb, kb, vtb, bias, ob);
    proj_kernel<<<dim3(DDIM / 64, BT / 64), 256, 0, stream>>>(ob, wprojT, out);
}

// Round 6
// 178.556 us; speedup vs baseline: 1.0711x; 1.0711x over previous
//
#include <hip/hip_runtime.h>
#include <hip/hip_bf16.h>

// (B,T,D,H) = (4,2048,384,6), HD=64. Inputs/output f32; intermediates bf16.
#define BB   4
#define TT   2048
#define DDIM 384
#define HH   6
#define HD   64
#define BT   (BB*TT)
#define QKVC (3*DDIM)

typedef __attribute__((ext_vector_type(4))) short short4v;
typedef __attribute__((ext_vector_type(8))) short short8v;
typedef __attribute__((ext_vector_type(4))) float float4v;
typedef unsigned short u16;

static __device__ __forceinline__ u16 f2bu(float f) {
    __hip_bfloat16 h = __float2bfloat16(f);
    return __builtin_bit_cast(u16, h);
}

static __device__ __forceinline__ short8v ld_frag(const u16* p) {
    short4v a = *(const short4v*)p;     // 2x b64: safe for 8B-aligned rows
    short4v b = *(const short4v*)(p + 4);
    return __builtin_shufflevector(a, b, 0, 1, 2, 3, 4, 5, 6, 7);
}

static __device__ __forceinline__ void st8(u16* p, uint4 v) {
    *(uint2*)p       = make_uint2(v.x, v.y);
    *(uint2*)(p + 4) = make_uint2(v.z, v.w);
}

#define MFMA16(a, b, c) __builtin_amdgcn_mfma_f32_16x16x32_bf16((a), (b), (c), 0, 0, 0)

// ---------------------------------------------------------------------------
// K0 (merged prep): blocks [0,108): wqkv^T ; [108,144): wproj^T ; [144,912):
// x -> bf16 cast.
// ---------------------------------------------------------------------------
__global__ __launch_bounds__(256) void prep_kernel(
    const float* __restrict__ wqkv, const float* __restrict__ wproj,
    const float* __restrict__ x,
    u16* __restrict__ wqkvT, u16* __restrict__ wprojT, u16* __restrict__ xb)
{
    const int bid = blockIdx.x;
    const int t = threadIdx.x;
    if (bid >= 144) {
        size_t base = (size_t)(bid - 144) * 4096 + (size_t)t * 16;
        const float* gp = x + base;
        __align__(16) u16 tmp[16];
        #pragma unroll
        for (int u = 0; u < 4; ++u) {
            float4 v = *(const float4*)(gp + 4 * u);
            tmp[4 * u + 0] = f2bu(v.x); tmp[4 * u + 1] = f2bu(v.y);
            tmp[4 * u + 2] = f2bu(v.z); tmp[4 * u + 3] = f2bu(v.w);
        }
        *(uint4*)(xb + base)     = *(const uint4*)tmp;
        *(uint4*)(xb + base + 8) = *(const uint4*)(tmp + 8);
        return;
    }
    const float* in; u16* out; int K, C, c0, k0;
    if (bid < 108) { in = wqkv;  out = wqkvT;  K = DDIM; C = QKVC;
                     c0 = (bid % 18) * 64; k0 = (bid / 18) * 64; }
    else           { int b2 = bid - 108; in = wproj; out = wprojT; K = DDIM; C = DDIM;
                     c0 = (b2 % 6) * 64; k0 = (b2 / 6) * 64; }
    __shared__ float tr[64][65];
    {
        int kr = t >> 2, cb = (t & 3) * 16;
        const float* gp = in + (size_t)(k0 + kr) * C + c0 + cb;
        #pragma unroll
        for (int u = 0; u < 4; ++u) {
            float4 v = *(const float4*)(gp + 4 * u);
            tr[cb + 4 * u + 0][kr] = v.x;
            tr[cb + 4 * u + 1][kr] = v.y;
            tr[cb + 4 * u + 2][kr] = v.z;
            tr[cb + 4 * u + 3][kr] = v.w;
        }
    }
    __syncthreads();
    {
        int c = t >> 2, kb = (t & 3) * 16;
        __align__(16) u16 tmp[16];
        #pragma unroll
        for (int u = 0; u < 16; ++u) tmp[u] = f2bu(tr[c][kb + u]);
        u16* op = out + (size_t)(c0 + c) * K + k0 + kb;
        *(uint4*)op       = *(const uint4*)tmp;
        *(uint4*)(op + 8) = *(const uint4*)(tmp + 8);
    }
}

// ---------------------------------------------------------------------------
// K1: qkv = xb @ wqkvT, RoPE fused in epilogue.
//   q,k -> [bh][t][d] bf16 ; v -> TRANSPOSED [bh][d][t] bf16.
// ---------------------------------------------------------------------------
__global__ __launch_bounds__(256) void qkv_rope_kernel(
    const u16* __restrict__ xb, const u16* __restrict__ wt,
    const float* __restrict__ cs, const float* __restrict__ sn,
    u16* __restrict__ qb, u16* __restrict__ kb, u16* __restrict__ vtb)
{
    __shared__ __align__(16) u16 xs[2][64][68];
    __shared__ __align__(16) u16 ws[2][64][68];
    const int t = threadIdx.x;
    const int wv = t >> 6, lane = t & 63, quad = lane >> 4, lo = lane & 15;
    const int r0 = blockIdx.y * 64;
    const int c0 = blockIdx.x * 64;
    const int sr = t >> 3, sd = (t & 7) * 8;

    st8(&xs[0][sr][sd],      *(const uint4*)(xb + (size_t)(r0 + sr) * DDIM + sd));
    st8(&xs[0][sr + 32][sd], *(const uint4*)(xb + (size_t)(r0 + sr + 32) * DDIM + sd));
    st8(&ws[0][sr][sd],      *(const uint4*)(wt + (size_t)(c0 + sr) * DDIM + sd));
    st8(&ws[0][sr + 32][sd], *(const uint4*)(wt + (size_t)(c0 + sr + 32) * DDIM + sd));
    __syncthreads();

    float4v acc[4] = {};
    for (int kk = 0; kk < 6; ++kk) {
        const int cur = kk & 1, nxt = cur ^ 1;
        const int kkn = (kk < 5 ? kk + 1 : 5) * 64;
        uint4 xp0 = *(const uint4*)(xb + (size_t)(r0 + sr) * DDIM + kkn + sd);
        uint4 xp1 = *(const uint4*)(xb + (size_t)(r0 + sr + 32) * DDIM + kkn + sd);
        uint4 wp0 = *(const uint4*)(wt + (size_t)(c0 + sr) * DDIM + kkn + sd);
        uint4 wp1 = *(const uint4*)(wt + (size_t)(c0 + sr + 32) * DDIM + kkn + sd);

        #pragma unroll
        for (int kf = 0; kf < 2; ++kf) {
            short8v a = ld_frag(&xs[cur][16 * wv + lo][kf * 32 + quad * 8]);
            #pragma unroll
            for (int nt = 0; nt < 4; ++nt) {
                short8v b = ld_frag(&ws[cur][nt * 16 + lo][kf * 32 + quad * 8]);
                acc[nt] = MFMA16(a, b, acc[nt]);
            }
        }
        st8(&xs[nxt][sr][sd], xp0);
        st8(&xs[nxt][sr + 32][sd], xp1);
        st8(&ws[nxt][sr][sd], wp0);
        st8(&ws[nxt][sr + 32][sd], wp1);
        __syncthreads();
    }

    const int sec = blockIdx.x / 6;     // 0=q, 1=k, 2=v
    const int h   = blockIdx.x % 6;
    const int rbase = r0 + 16 * wv + 4 * quad;
    const int bidx  = r0 >> 11;
    const int tbase = rbase & (TT - 1);

    if (sec == 2) {
        #pragma unroll
        for (int nt = 0; nt < 4; ++nt) {
            int d = nt * 16 + lo;
            unsigned a0 = f2bu(acc[nt][0]) | ((unsigned)f2bu(acc[nt][1]) << 16);
            unsigned a1 = f2bu(acc[nt][2]) | ((unsigned)f2bu(acc[nt][3]) << 16);
            u16* gp = vtb + ((size_t)(bidx * HH + h) * HD + d) * TT + tbase;
            *(uint2*)gp = make_uint2(a0, a1);
        }
    } else {
        u16* dst = (sec == 0) ? qb : kb;
        #pragma unroll
        for (int np = 0; np < 2; ++np) {
            #pragma unroll
            for (int r = 0; r < 4; ++r) {
                int tpos = tbase + r;
                int ci = np * 16 + lo;
                float cv = cs[tpos * 32 + ci];
                float sv = sn[tpos * 32 + ci];
                float x1 = acc[np][r], x2 = acc[np + 2][r];
                u16* gp = dst + ((size_t)(bidx * HH + h) * TT + tpos) * HD;
                gp[ci]      = f2bu(x1 * cv - x2 * sv);
                gp[ci + 32] = f2bu(x2 * cv + x1 * sv);
            }
        }
    }
}

// ---------------------------------------------------------------------------
// K2: MFMA flash attention, S^T formulation + K=32 PV:
//   S^T = K·Q^T (C-layout: lane holds P(q=lo, k=nt*16+4*quad+r) — 4 CONTIGUOUS
//   k per q-row) -> P transform to A-layout = 4 ds_write_b64 + 2 ds_read_b128
//   into a wave-private buffer (in-order DS pipe, no barrier). PV back on
//   16x16x32 (8 MFMA). Grid (bh, q): XCD = bh%8 -> 3 bh/XCD = 1.5MB K/V in L2.
// ---------------------------------------------------------------------------
__global__ __launch_bounds__(256, 3) void attn_kernel(
    const u16* __restrict__ qb, const u16* __restrict__ kb, const u16* __restrict__ vtb,
    const float* __restrict__ bias, u16* __restrict__ ob)
{
    __shared__ __align__(16) u16 ks[2][64][68];
    __shared__ __align__(16) u16 vt[2][64][68];
    __shared__ __align__(16) u16 ps[4][16][72];   // stride 72 -> 16B-aligned rows

    const int t = threadIdx.x;
    const int wv = t >> 6, lane = t & 63, quad = lane >> 4, lo = lane & 15;
    const int bh = blockIdx.x;                    // bh fastest: XCD = bh % 8
    const int b = bh / HH, h = bh % HH;
    const int q0 = blockIdx.y * 64;
    const int qrow = q0 + 16 * wv + lo;           // q-row owned by this lane

    // Q fragments (B-operand of S^T): straight from global, row-contiguous
    const u16* qbase = qb + ((size_t)bh * TT + qrow) * HD + quad * 8;
    short8v aq0 = __builtin_bit_cast(short8v, *(const uint4*)qbase);
    short8v aq1 = __builtin_bit_cast(short8v, *(const uint4*)(qbase + 32));

    const int sr = t >> 3, sd = (t & 7) * 8;
    const u16* kbbase = kb + (size_t)bh * TT * HD;
    const u16* vtbase = vtb + (size_t)bh * HD * TT;
    const float* brow = bias + (size_t)qrow * TT + 4 * quad;

    st8(&ks[0][sr][sd],      *(const uint4*)(kbbase + (size_t)sr * HD + sd));
    st8(&ks[0][sr + 32][sd], *(const uint4*)(kbbase + (size_t)(sr + 32) * HD + sd));
    st8(&vt[0][sr][sd],      *(const uint4*)(vtbase + (size_t)sr * TT + sd));
    st8(&vt[0][sr + 32][sd], *(const uint4*)(vtbase + (size_t)(sr + 32) * TT + sd));
    float4 bcur[4];
    #pragma unroll
    for (int nt = 0; nt < 4; ++nt) bcur[nt] = *(const float4*)(brow + nt * 16);
    __syncthreads();

    float4v oacc[4] = {};                 // [dt]: O(q=16wv+4*quad+r, d=16dt+lo)
    float lacc[4] = {0.f, 0.f, 0.f, 0.f}; // partial row-sums for q-row = lo

    for (int kt = 0; kt < TT / 64; ++kt) {
        const int cur = kt & 1, nxt = cur ^ 1;
        const int kn = (kt < 31 ? kt + 1 : 31) * 64;

        uint4 kp0 = *(const uint4*)(kbbase + (size_t)(kn + sr) * HD + sd);
        uint4 kp1 = *(const uint4*)(kbbase + (size_t)(kn + sr + 32) * HD + sd);
        uint4 vp0 = *(const uint4*)(vtbase + (size_t)sr * TT + kn + sd);
        uint4 vp1 = *(const uint4*)(vtbase + (size_t)(sr + 32) * TT + kn + sd);
        float4 bnxt[4];
        #pragma unroll
        for (int nt = 0; nt < 4; ++nt) bnxt[nt] = *(const float4*)(brow + kn + nt * 16);

        // S^T = K Q^T : A = K-frag (m = k-col), B = Q-frag (n = q-row)
        float4v s[4] = {};
        #pragma unroll
        for (int kf = 0; kf < 2; ++kf) {
            #pragma unroll
            for (int nt = 0; nt < 4; ++nt) {
                short8v kfr = ld_frag(&ks[cur][nt * 16 + lo][kf * 32 + quad * 8]);
                s[nt] = MFMA16(kfr, (kf ? aq1 : aq0), s[nt]);
            }
        }

        // exp (unshifted) -> wave-private ps, 4 contiguous k per b64 write
        #pragma unroll
        for (int nt = 0; nt < 4; ++nt) {
            float p0 = __expf(fmaf(s[nt][0], 0.125f, bcur[nt].x));
            float p1 = __expf(fmaf(s[nt][1], 0.125f, bcur[nt].y));
            float p2 = __expf(fmaf(s[nt][2], 0.125f, bcur[nt].z));
            float p3 = __expf(fmaf(s[nt][3], 0.125f, bcur[nt].w));
            lacc[nt] += (p0 + p1) + (p2 + p3);
            short4v pv = { (short)f2bu(p0), (short)f2bu(p1),
                           (short)f2bu(p2), (short)f2bu(p3) };
            *(short4v*)&ps[wv][lo][nt * 16 + 4 * quad] = pv;   // ds_write_b64
        }

        // O += P V  via 16x16x32: A = ps row lo (b128), B = V^T lane-local
        #pragma unroll
        for (int kf = 0; kf < 2; ++kf) {
            short8v ap = __builtin_bit_cast(short8v,
                *(const uint4*)&ps[wv][lo][kf * 32 + quad * 8]);  // ds_read_b128
            #pragma unroll
            for (int dt = 0; dt < 4; ++dt) {
                short8v bv = ld_frag(&vt[cur][dt * 16 + lo][kf * 32 + quad * 8]);
                oacc[dt] = MFMA16(ap, bv, oacc[dt]);
            }
        }

        st8(&ks[nxt][sr][sd], kp0);
        st8(&ks[nxt][sr + 32][sd], kp1);
        st8(&vt[nxt][sr][sd], vp0);
        st8(&vt[nxt][sr + 32][sd], vp1);
        #pragma unroll
        for (int nt = 0; nt < 4; ++nt) bcur[nt] = bnxt[nt];
        __syncthreads();
    }

    float l = (lacc[0] + lacc[1]) + (lacc[2] + lacc[3]);
    l += __shfl_xor(l, 16);
    l += __shfl_xor(l, 32);                 // all lanes hold l(row=lo)
    #pragma unroll
    for (int r = 0; r < 4; ++r) {
        float lr = __shfl(l, 4 * quad + r); // l for output row 4*quad+r
        float inv = 1.f / lr;
        u16* gp = ob + ((size_t)b * TT + q0 + 16 * wv + 4 * quad + r) * DDIM + h * HD + lo;
        #pragma unroll
        for (int dt = 0; dt < 4; ++dt)
            gp[dt * 16] = f2bu(oacc[dt][r] * inv);
    }
}

// ---------------------------------------------------------------------------
// K3: out = O @ w_proj (MFMA), f32 output. Ping-pong + prefetch.
// ---------------------------------------------------------------------------
__global__ __launch_bounds__(256) void proj_kernel(
    const u16* __restrict__ o, const u16* __restrict__ wt, float* __restrict__ out)
{
    __shared__ __align__(16) u16 os[2][64][68];
    __shared__ __align__(16) u16 ws[2][64][68];
    const int t = threadIdx.x;
    const int wv = t >> 6, lane = t & 63, quad = lane >> 4, lo = lane & 15;
    const int r0 = blockIdx.y * 64, c0 = blockIdx.x * 64;
    const int sr = t >> 3, sd = (t & 7) * 8;

    st8(&os[0][sr][sd],      *(const uint4*)(o + (size_t)(r0 + sr) * DDIM + sd));
    st8(&os[0][sr + 32][sd], *(const uint4*)(o + (size_t)(r0 + sr + 32) * DDIM + sd));
    st8(&ws[0][sr][sd],      *(const uint4*)(wt + (size_t)(c0 + sr) * DDIM + sd));
    st8(&ws[0][sr + 32][sd], *(const uint4*)(wt + (size_t)(c0 + sr + 32) * DDIM + sd));
    __syncthreads();

    float4v acc[4] = {};
    for (int kk = 0; kk < 6; ++kk) {
        const int cur = kk & 1, nxt = cur ^ 1;
        const int kkn = (kk < 5 ? kk + 1 : 5) * 64;
        uint4 op0 = *(const uint4*)(o + (size_t)(r0 + sr) * DDIM + kkn + sd);
        uint4 op1 = *(const uint4*)(o + (size_t)(r0 + sr + 32) * DDIM + kkn + sd);
        uint4 wp0 = *(const uint4*)(wt + (size_t)(c0 + sr) * DDIM + kkn + sd);
        uint4 wp1 = *(const uint4*)(wt + (size_t)(c0 + sr + 32) * DDIM + kkn + sd);

        #pragma unroll
        for (int kf = 0; kf < 2; ++kf) {
            short8v a = ld_frag(&os[cur][16 * wv + lo][kf * 32 + quad * 8]);
            #pragma unroll
            for (int nt = 0; nt < 4; ++nt) {
                short8v bfr = ld_frag(&ws[cur][nt * 16 + lo][kf * 32 + quad * 8]);
                acc[nt] = MFMA16(a, bfr, acc[nt]);
            }
        }
        st8(&os[nxt][sr][sd], op0);
        st8(&os[nxt][sr + 32][sd], op1);
        st8(&ws[nxt][sr][sd], wp0);
        st8(&ws[nxt][sr + 32][sd], wp1);
        __syncthreads();
    }
    #pragma unroll
    for (int r = 0; r < 4; ++r) {
        float* gp = out + (size_t)(r0 + 16 * wv + 4 * quad + r) * DDIM + c0;
        #pragma unroll
        for (int nt = 0; nt < 4; ++nt)
            gp[nt * 16 + lo] = acc[nt][r];
    }
}

extern "C" void kernel_launch(void* const* d_in, const int* in_sizes, int n_in,
                              void* d_out, int out_size, void* d_ws, size_t ws_size,
                              hipStream_t stream) {
    const float* x     = (const float*)d_in[0];
    const float* bias  = (const float*)d_in[1];
    const float* cs    = (const float*)d_in[2];
    const float* sn    = (const float*)d_in[3];
    const float* wqkv  = (const float*)d_in[4];
    const float* wproj = (const float*)d_in[5];
    float* out = (float*)d_out;

    u16* wqkvT  = (u16*)d_ws;                         // [1152][384]
    u16* wprojT = wqkvT + (size_t)QKVC * DDIM;        // [384][384]
    u16* qb     = wprojT + (size_t)DDIM * DDIM;       // [bh][t][d]
    u16* kb     = qb + (size_t)BB * HH * TT * HD;     // [bh][t][d]
    u16* vtb    = kb + (size_t)BB * HH * TT * HD;     // [bh][d][t]
    u16* ob     = vtb + (size_t)BB * HH * TT * HD;    // [b][t][h*64+d]
    u16* xb     = ob + (size_t)BT * DDIM;             // [b*t][384] bf16 x

    prep_kernel<<<dim3(144 + BT * DDIM / 4096), 256, 0, stream>>>(
        wqkv, wproj, x, wqkvT, wprojT, xb);
    qkv_rope_kernel<<<dim3(QKVC / 64, BT / 64), 256, 0, stream>>>(
        xb, wqkvT, cs, sn, qb, kb, vtb);
    attn_kernel<<<dim3(BB * HH, TT / 64), 256, 0, stream>>>(qb, kb, vtb, bias, ob);
    proj_kernel<<<dim3(DDIM / 64, BT / 64), 256, 0, stream>>>(ob, wprojT, out);
}